// Round 17
// baseline (114.317 us; speedup 1.0000x reference)
//
#include <hip/hip_runtime.h>
#include <hip/hip_bf16.h>

constexpr int B = 2, S = 2048, D = 1024, H = 16, Hd = 64;
constexpr int M = B * S;   // 4096 rows
constexpr int K = 1024;

typedef __attribute__((ext_vector_type(8))) short short8;
typedef __attribute__((ext_vector_type(4))) float f32x4;

#if __has_builtin(__builtin_amdgcn_exp2f)
#define EXP2F __builtin_amdgcn_exp2f
#else
#define EXP2F exp2f
#endif

__device__ __forceinline__ float bf2f(unsigned short u) {
    return __uint_as_float(((unsigned)u) << 16);
}
__device__ __forceinline__ unsigned short f2bf(float f) {   // RNE
    unsigned u = __float_as_uint(f);
    u += 0x7FFF + ((u >> 16) & 1);
    return (unsigned short)(u >> 16);
}
__device__ __forceinline__ void gload_lds16(const unsigned short* g, unsigned short* l) {
    __builtin_amdgcn_global_load_lds(
        (const __attribute__((address_space(1))) void*)g,
        (__attribute__((address_space(3))) void*)l, 16, 0, 0);
}

// ---------------------------------------------------------------------------
// x fp32 -> bf16, 8 elems/thread
// ---------------------------------------------------------------------------
__global__ __launch_bounds__(256) void convert_x_kernel(
    const float* __restrict__ x, unsigned short* __restrict__ xb)
{
    const size_t i = ((size_t)blockIdx.x * 256 + threadIdx.x) * 8;
    float4 a = *(const float4*)(x + i), b = *(const float4*)(x + i + 4);
    ushort4 u0 = {f2bf(a.x), f2bf(a.y), f2bf(a.z), f2bf(a.w)};
    ushort4 u1 = {f2bf(b.x), f2bf(b.y), f2bf(b.z), f2bf(b.w)};
    *(ushort4*)(xb + i) = u0;
    *(ushort4*)(xb + i + 4) = u1;
}

// ---------------------------------------------------------------------------
// Weight transpose+convert: w [K,N] fp32 -> wt [N,K] bf16 (padded-LDS tile).
// ---------------------------------------------------------------------------
__global__ __launch_bounds__(256) void transpose_w_kernel(
    const float* __restrict__ wq, const float* __restrict__ wk,
    const float* __restrict__ wv, const float* __restrict__ wo,
    unsigned short* __restrict__ wqkv_t, unsigned short* __restrict__ wo_t)
{
    __shared__ float tile[64][65];
    const int z = blockIdx.z;
    const float* w = (z == 0) ? wq : (z == 1) ? wk : (z == 2) ? wv : wo;
    unsigned short* dst = (z == 3) ? wo_t : wqkv_t + (size_t)z * K * K;
    const int k0 = blockIdx.x * 64, n0 = blockIdx.y * 64;
    const int t = threadIdx.x;
    #pragma unroll
    for (int it = 0; it < 16; ++it) {
        int idx = t + it * 256;
        tile[idx >> 6][idx & 63] = w[(size_t)(k0 + (idx >> 6)) * K + n0 + (idx & 63)];
    }
    __syncthreads();
    #pragma unroll
    for (int it = 0; it < 16; ++it) {
        int idx = t + it * 256;
        int r = idx >> 6, c = idx & 63;
        dst[(size_t)(n0 + r) * K + k0 + c] = f2bf(tile[c][r]);
    }
}

// ---------------------------------------------------------------------------
// Fused QKV MFMA GEMM (R14-proven BK=32 single-buffer m97 structure).
// Q written PRE-SCALED by 0.125*log2(e) (exp2-domain attention).
// ---------------------------------------------------------------------------
__global__ __launch_bounds__(256) void qkv_mfma_kernel(
    const unsigned short* __restrict__ xa, const unsigned short* __restrict__ bt,
    unsigned short* __restrict__ q, unsigned short* __restrict__ k,
    unsigned short* __restrict__ vt)
{
    __shared__ unsigned short A_lds[128][32];
    __shared__ unsigned short B_lds[128][32];
    const int t = threadIdx.x, w = t >> 6, l = t & 63;
    const int lr = l & 15, lg = l >> 4;
    const int wm = w >> 1, wn = w & 1;
    const int m0 = blockIdx.x * 128, n0 = blockIdx.y * 128;
    const int srow = l >> 2, skofs = (l & 3) * 8;

    f32x4 acc[4][4];
    #pragma unroll
    for (int i = 0; i < 4; ++i)
        #pragma unroll
        for (int j = 0; j < 4; ++j) acc[i][j] = (f32x4){0.f, 0.f, 0.f, 0.f};

    for (int k0 = 0; k0 < K; k0 += 32) {
        #pragma unroll
        for (int p = 0; p < 2; ++p) {
            const int c = w * 2 + p;
            gload_lds16(xa + (size_t)(m0 + c * 16 + srow) * K + k0 + skofs, &A_lds[c * 16][0]);
            gload_lds16(bt + (size_t)(n0 + c * 16 + srow) * K + k0 + skofs, &B_lds[c * 16][0]);
        }
        __syncthreads();
        short8 af[4], bf[4];
        #pragma unroll
        for (int i = 0; i < 4; ++i) af[i] = *(const short8*)&A_lds[wm * 64 + i * 16 + lr][lg * 8];
        #pragma unroll
        for (int j = 0; j < 4; ++j) bf[j] = *(const short8*)&B_lds[wn * 64 + j * 16 + lr][lg * 8];
        #pragma unroll
        for (int i = 0; i < 4; ++i)
            #pragma unroll
            for (int j = 0; j < 4; ++j)
                acc[i][j] = __builtin_amdgcn_mfma_f32_16x16x32_bf16(af[i], bf[j], acc[i][j], 0, 0, 0);
        __syncthreads();
    }

    const int z = (n0 >> 10);
    const float scale = (z == 0) ? 0.125f * 1.44269504f : 1.0f;
    #pragma unroll
    for (int i = 0; i < 4; ++i) {
        const int mbase = m0 + wm * 64 + i * 16 + lg * 4;
        #pragma unroll
        for (int j = 0; j < 4; ++j) {
            const int n = n0 + wn * 64 + j * 16 + lr;
            const int nn = n & 1023, hh = nn >> 6, hd = nn & 63;
            #pragma unroll
            for (int r = 0; r < 4; ++r) {
                const int mm = mbase + r, bb = mm >> 11, ss = mm & (S - 1);
                const unsigned short val = f2bf(acc[i][j][r] * scale);
                if (z == 0)      q[((size_t)(bb * H + hh) * S + ss) * Hd + hd] = val;
                else if (z == 1) k[((size_t)(bb * H + hh) * S + ss) * Hd + hd] = val;
                else             vt[((size_t)(bb * H + hh) * Hd + hd) * S + ss] = val;
            }
        }
    }
}

// ---------------------------------------------------------------------------
// Output projection MFMA GEMM (R14-proven BK=32 single-buffer structure).
// ---------------------------------------------------------------------------
__global__ __launch_bounds__(256) void out_mfma_kernel(
    const unsigned short* __restrict__ a, const unsigned short* __restrict__ bt,
    const float* __restrict__ bias, float* __restrict__ out)
{
    __shared__ unsigned short A_lds[128][32];
    __shared__ unsigned short B_lds[128][32];
    const int t = threadIdx.x, w = t >> 6, l = t & 63;
    const int lr = l & 15, lg = l >> 4;
    const int wm = w >> 1, wn = w & 1;
    const int m0 = blockIdx.x * 128, n0 = blockIdx.y * 128;
    const int srow = l >> 2, skofs = (l & 3) * 8;

    f32x4 acc[4][4];
    #pragma unroll
    for (int i = 0; i < 4; ++i)
        #pragma unroll
        for (int j = 0; j < 4; ++j) acc[i][j] = (f32x4){0.f, 0.f, 0.f, 0.f};

    for (int k0 = 0; k0 < K; k0 += 32) {
        #pragma unroll
        for (int p = 0; p < 2; ++p) {
            const int c = w * 2 + p;
            gload_lds16(a  + (size_t)(m0 + c * 16 + srow) * K + k0 + skofs, &A_lds[c * 16][0]);
            gload_lds16(bt + (size_t)(n0 + c * 16 + srow) * K + k0 + skofs, &B_lds[c * 16][0]);
        }
        __syncthreads();
        short8 af[4], bf[4];
        #pragma unroll
        for (int i = 0; i < 4; ++i) af[i] = *(const short8*)&A_lds[wm * 64 + i * 16 + lr][lg * 8];
        #pragma unroll
        for (int j = 0; j < 4; ++j) bf[j] = *(const short8*)&B_lds[wn * 64 + j * 16 + lr][lg * 8];
        #pragma unroll
        for (int i = 0; i < 4; ++i)
            #pragma unroll
            for (int j = 0; j < 4; ++j)
                acc[i][j] = __builtin_amdgcn_mfma_f32_16x16x32_bf16(af[i], bf[j], acc[i][j], 0, 0, 0);
        __syncthreads();
    }

    #pragma unroll
    for (int i = 0; i < 4; ++i) {
        const int mbase = m0 + wm * 64 + i * 16 + lg * 4;
        #pragma unroll
        for (int j = 0; j < 4; ++j) {
            const int n = n0 + wn * 64 + j * 16 + lr;
            const float bv = bias[n];
            #pragma unroll
            for (int r = 0; r < 4; ++r)
                out[(size_t)(mbase + r) * D + n] = acc[i][j][r] + bv;
        }
    }
}

// ---------------------------------------------------------------------------
// MFMA causal flash attention, v12 = R15 peeled-diag + DBUF K/V, ONE barrier:
//  - Kb[2]/Vb[2] (32 KB) + swizzled P (8 KB) = 40 KB; grid caps residency at
//    4 blocks/CU anyway, so the extra LDS is free.
//  - iter t: stage(t+1)->regs; compute from buf[cur]; publish -> buf[cur^1];
//    ONE __syncthreads. Reads of buf[cur^1] finished before the PREVIOUS
//    barrier, so publish cannot race.
//  - per-CU block mix {c, 31-c, c+8, 23-c}: no CU gets two 32-tile chains.
//  - fixed-reference softmax (exp2(s-16), deferred l-reduce), XCD-locality.
// ---------------------------------------------------------------------------
__global__ __launch_bounds__(256) void attn_mfma_kernel(
    const unsigned short* __restrict__ q, const unsigned short* __restrict__ k,
    const unsigned short* __restrict__ vt, unsigned short* __restrict__ ctx)
{
    __shared__ unsigned short Kb[2][64 * 64];
    __shared__ unsigned short Vb[2][64 * 64];
    __shared__ unsigned short P_lds[4][16 * 64];
    const int t = threadIdx.x, w = t >> 6, l = t & 63;
    const int lr = l & 15, lg = l >> 4;

    // XCD-locality decomposition + balanced per-CU qt mix
    const int bid = blockIdx.x;          // 0..1023
    const int xcd = bid & 7;
    const int j   = bid >> 3;            // 0..127
    const int m   = j >> 5;              // 0..3: bh-group within XCD
    const int c0  = j & 31;
    const int bh  = xcd * 4 + m;         // 0..31
    const int bb  = bh >> 4, hh = bh & 15;
    const int cc  = (c0 + ((m >> 1) ? 8 : 0)) & 31;
    const int qt  = (m & 1) ? (31 - cc) : cc;

    const int q0 = qt * 64 + w * 16;
    const int diag = qt;
    const size_t base  = (size_t)(bb * H + hh) * S * Hd;
    const size_t vbase = (size_t)(bb * H + hh) * Hd * S;
    const int pswz = (lr & 7) << 3;      // P_lds XOR swizzle (ushort units)

    const int srow0 = w * 16 + (l >> 3);      // staging: wave owns 16 rows
    const int scol  = (l & 7) * 8;

    short8 qf[2];
    #pragma unroll
    for (int ci = 0; ci < 2; ++ci)
        qf[ci] = *(const short8*)(q + base + (size_t)(q0 + lr) * Hd + ci * 32 + lg * 8);

    f32x4 accO[4];   // O^T: accO[hb][r] = O^T[hb*16+lg*4+r][q=lr]
    #pragma unroll
    for (int hb = 0; hb < 4; ++hb) accO[hb] = (f32x4){0.f, 0.f, 0.f, 0.f};
    float l_part = 0.f;   // per-lane partial sum of exp2(s-16)

    // prologue: tile 0 -> regs -> buf 0
    {
        short8 k0r[2], v0r[2];
        #pragma unroll
        for (int it = 0; it < 2; ++it) {
            const int row = srow0 + it * 8;
            k0r[it] = *(const short8*)(k + base + (size_t)row * Hd + scol);
            v0r[it] = *(const short8*)(vt + vbase + (size_t)row * S + scol);
        }
        #pragma unroll
        for (int it = 0; it < 2; ++it) {
            const int row = srow0 + it * 8;
            const int wc = (scol ^ ((row & 7) * 8));
            *(short8*)&Kb[0][row * 64 + wc] = k0r[it];
            *(short8*)&Vb[0][row * 64 + wc] = v0r[it];
        }
    }
    __syncthreads();

    int cur = 0;
    // ======== main loop: unmasked tiles 0..diag-1, ONE barrier each ========
    for (int kt = 0; kt < diag; ++kt) {
        // stage next tile into regs (latency hides under compute)
        short8 nK[2], nV[2];
        {
            const unsigned short* kg = k + base + (size_t)(kt + 1) * 64 * Hd;
            const unsigned short* vg = vt + vbase + (size_t)(kt + 1) * 64;
            #pragma unroll
            for (int it = 0; it < 2; ++it) {
                const int row = srow0 + it * 8;
                nK[it] = *(const short8*)(kg + (size_t)row * Hd + scol);
                nV[it] = *(const short8*)(vg + (size_t)row * S + scol);
            }
        }

        const unsigned short* Kc = Kb[cur];
        const unsigned short* Vc = Vb[cur];

        // S^T = K Q^T
        f32x4 accS[4];
        __builtin_amdgcn_s_setprio(1);
        #pragma unroll
        for (int kc = 0; kc < 4; ++kc) {
            accS[kc] = (f32x4){0.f, 0.f, 0.f, 0.f};
            const int krow = kc * 16 + lr;
            #pragma unroll
            for (int ci = 0; ci < 2; ++ci) {
                short8 kf = *(const short8*)&Kc[krow * 64 +
                    ((ci * 32 + lg * 8) ^ ((krow & 7) * 8))];
                accS[kc] = __builtin_amdgcn_mfma_f32_16x16x32_bf16(kf, qf[ci], accS[kc], 0, 0, 0);
            }
        }
        __builtin_amdgcn_s_setprio(0);

        // fixed-reference softmax
        float ps[16];
        #pragma unroll
        for (int i = 0; i < 16; ++i)
            ps[i] = EXP2F(accS[i >> 2][i & 3] - 16.f);
        float s8[8];
        #pragma unroll
        for (int i = 0; i < 8; ++i) s8[i] = ps[i] + ps[i + 8];
        l_part += ((s8[0] + s8[4]) + (s8[1] + s8[5])) +
                  ((s8[2] + s8[6]) + (s8[3] + s8[7]));

        // P -> per-wave LDS (swizzled b64), re-read as B-frags
        #pragma unroll
        for (int kc = 0; kc < 4; ++kc) {
            uint2 pk;
            *(__hip_bfloat162*)&pk.x =
                __float22bfloat162_rn(make_float2(ps[kc * 4 + 0], ps[kc * 4 + 1]));
            *(__hip_bfloat162*)&pk.y =
                __float22bfloat162_rn(make_float2(ps[kc * 4 + 2], ps[kc * 4 + 3]));
            *(uint2*)&P_lds[w][lr * 64 + ((kc * 16 + lg * 4) ^ pswz)] = pk;
        }
        short8 pa[2];
        #pragma unroll
        for (int ci = 0; ci < 2; ++ci)
            pa[ci] = *(const short8*)&P_lds[w][lr * 64 + ((ci * 32 + lg * 8) ^ pswz)];

        // O^T += V^T P^T
        __builtin_amdgcn_s_setprio(1);
        #pragma unroll
        for (int hb = 0; hb < 4; ++hb) {
            const int vrow = hb * 16 + lr;
            #pragma unroll
            for (int ci = 0; ci < 2; ++ci) {
                short8 vf = *(const short8*)&Vc[vrow * 64 +
                    ((ci * 32 + lg * 8) ^ ((vrow & 7) * 8))];
                accO[hb] = __builtin_amdgcn_mfma_f32_16x16x32_bf16(vf, pa[ci], accO[hb], 0, 0, 0);
            }
        }
        __builtin_amdgcn_s_setprio(0);

        // publish next tile into the OTHER buffer; one barrier
        #pragma unroll
        for (int it = 0; it < 2; ++it) {
            const int row = srow0 + it * 8;
            const int wc = (scol ^ ((row & 7) * 8));
            *(short8*)&Kb[cur ^ 1][row * 64 + wc] = nK[it];
            *(short8*)&Vb[cur ^ 1][row * 64 + wc] = nV[it];
        }
        __syncthreads();
        cur ^= 1;
    }

    // ======== diagonal (masked) tile ========
    {
        const unsigned short* Kc = Kb[cur];
        const unsigned short* Vc = Vb[cur];
        f32x4 accS[4];
        __builtin_amdgcn_s_setprio(1);
        #pragma unroll
        for (int kc = 0; kc < 4; ++kc) {
            accS[kc] = (f32x4){0.f, 0.f, 0.f, 0.f};
            const int krow = kc * 16 + lr;
            #pragma unroll
            for (int ci = 0; ci < 2; ++ci) {
                short8 kf = *(const short8*)&Kc[krow * 64 +
                    ((ci * 32 + lg * 8) ^ ((krow & 7) * 8))];
                accS[kc] = __builtin_amdgcn_mfma_f32_16x16x32_bf16(kf, qf[ci], accS[kc], 0, 0, 0);
            }
        }
        __builtin_amdgcn_s_setprio(0);

        float ps[16];
        #pragma unroll
        for (int kc = 0; kc < 4; ++kc)
            #pragma unroll
            for (int r = 0; r < 4; ++r) {
                float s = accS[kc][r];
                if (kc * 16 + lg * 4 + r > w * 16 + lr) s = -INFINITY;
                ps[kc * 4 + r] = EXP2F(s - 16.f);
            }
        float s8[8];
        #pragma unroll
        for (int i = 0; i < 8; ++i) s8[i] = ps[i] + ps[i + 8];
        l_part += ((s8[0] + s8[4]) + (s8[1] + s8[5])) +
                  ((s8[2] + s8[6]) + (s8[3] + s8[7]));

        #pragma unroll
        for (int kc = 0; kc < 4; ++kc) {
            uint2 pk;
            *(__hip_bfloat162*)&pk.x =
                __float22bfloat162_rn(make_float2(ps[kc * 4 + 0], ps[kc * 4 + 1]));
            *(__hip_bfloat162*)&pk.y =
                __float22bfloat162_rn(make_float2(ps[kc * 4 + 2], ps[kc * 4 + 3]));
            *(uint2*)&P_lds[w][lr * 64 + ((kc * 16 + lg * 4) ^ pswz)] = pk;
        }
        short8 pa[2];
        #pragma unroll
        for (int ci = 0; ci < 2; ++ci)
            pa[ci] = *(const short8*)&P_lds[w][lr * 64 + ((ci * 32 + lg * 8) ^ pswz)];

        __builtin_amdgcn_s_setprio(1);
        #pragma unroll
        for (int hb = 0; hb < 4; ++hb) {
            const int vrow = hb * 16 + lr;
            #pragma unroll
            for (int ci = 0; ci < 2; ++ci) {
                short8 vf = *(const short8*)&Vc[vrow * 64 +
                    ((ci * 32 + lg * 8) ^ ((vrow & 7) * 8))];
                accO[hb] = __builtin_amdgcn_mfma_f32_16x16x32_bf16(vf, pa[ci], accO[hb], 0, 0, 0);
            }
        }
        __builtin_amdgcn_s_setprio(0);
    }

    // ---- epilogue: one deferred l-reduce ----
    float l_run = l_part;
    l_run += __shfl_xor(l_run, 16);
    l_run += __shfl_xor(l_run, 32);
    const float inv = 1.f / l_run;
    unsigned short* crow = ctx + (size_t)(bb * S + q0 + lr) * D + hh * Hd + lg * 4;
    #pragma unroll
    for (int hb = 0; hb < 4; ++hb) {
        ushort4 o;
        o.x = f2bf(accO[hb][0] * inv);
        o.y = f2bf(accO[hb][1] * inv);
        o.z = f2bf(accO[hb][2] * inv);
        o.w = f2bf(accO[hb][3] * inv);
        *(ushort4*)(crow + hb * 16) = o;
    }
}

extern "C" void kernel_launch(void* const* d_in, const int* in_sizes, int n_in,
                              void* d_out, int out_size, void* d_ws, size_t ws_size,
                              hipStream_t stream) {
    const float* x  = (const float*)d_in[0];
    const float* wq = (const float*)d_in[1];
    const float* wk = (const float*)d_in[2];
    const float* wv = (const float*)d_in[3];
    const float* wo = (const float*)d_in[4];
    const float* bo = (const float*)d_in[5];
    float* out = (float*)d_out;

    char* ws = (char*)d_ws;
    unsigned short* x_bf   = (unsigned short*)ws;
    unsigned short* q      = (unsigned short*)(ws + ((size_t)8  << 20));
    unsigned short* kk     = (unsigned short*)(ws + ((size_t)16 << 20));
    unsigned short* vt     = (unsigned short*)(ws + ((size_t)24 << 20));
    unsigned short* ctx    = x_bf;
    unsigned short* wqkv_t = (unsigned short*)(ws + ((size_t)32 << 20));
    unsigned short* wo_t   = (unsigned short*)(ws + ((size_t)38 << 20));

    convert_x_kernel<<<(M * K) / (256 * 8), 256, 0, stream>>>(x, x_bf);
    dim3 gtr(K / 64, K / 64, 4);
    transpose_w_kernel<<<gtr, 256, 0, stream>>>(wq, wk, wv, wo, wqkv_t, wo_t);

    dim3 gqkv(M / 128, 3072 / 128);
    qkv_mfma_kernel<<<gqkv, 256, 0, stream>>>(x_bf, wqkv_t, q, kk, vt);

    attn_mfma_kernel<<<1024, 256, 0, stream>>>(q, kk, vt, ctx);

    dim3 gout(M / 128, D / 128);
    out_mfma_kernel<<<gout, 256, 0, stream>>>(ctx, wo_t, bo, out);
}

// Round 18
// 110.933 us; speedup vs baseline: 1.0305x; 1.0305x over previous
//
#include <hip/hip_runtime.h>
#include <hip/hip_bf16.h>

constexpr int B = 2, S = 2048, D = 1024, H = 16, Hd = 64;
constexpr int M = B * S;   // 4096 rows
constexpr int K = 1024;

typedef __attribute__((ext_vector_type(8))) short short8;
typedef __attribute__((ext_vector_type(4))) float f32x4;

#if __has_builtin(__builtin_amdgcn_exp2f)
#define EXP2F __builtin_amdgcn_exp2f
#else
#define EXP2F exp2f
#endif

__device__ __forceinline__ float bf2f(unsigned short u) {
    return __uint_as_float(((unsigned)u) << 16);
}
__device__ __forceinline__ unsigned short f2bf(float f) {   // RNE
    unsigned u = __float_as_uint(f);
    u += 0x7FFF + ((u >> 16) & 1);
    return (unsigned short)(u >> 16);
}
__device__ __forceinline__ void gload_lds16(const unsigned short* g, unsigned short* l) {
    __builtin_amdgcn_global_load_lds(
        (const __attribute__((address_space(1))) void*)g,
        (__attribute__((address_space(3))) void*)l, 16, 0, 0);
}

// ---------------------------------------------------------------------------
// Prep: z=0..3 -> weight transpose+convert (w [K,N] fp32 -> wt [N,K] bf16);
//       z=4    -> x fp32 -> bf16. One launch instead of two.
// ---------------------------------------------------------------------------
__global__ __launch_bounds__(256) void prep_kernel(
    const float* __restrict__ x,
    const float* __restrict__ wq, const float* __restrict__ wk,
    const float* __restrict__ wv, const float* __restrict__ wo,
    unsigned short* __restrict__ xb,
    unsigned short* __restrict__ wqkv_t, unsigned short* __restrict__ wo_t)
{
    __shared__ float tile[64][65];
    const int z = blockIdx.z;
    const int t = threadIdx.x;
    if (z == 4) {   // x conversion: 256 blocks x 256 thr x 8 iters x 8 elems
        const int bid = blockIdx.y * 16 + blockIdx.x;
        const size_t base_i = ((size_t)bid * 256 + t) * 8;
        #pragma unroll
        for (int it = 0; it < 8; ++it) {
            const size_t i = base_i + (size_t)it * 524288;
            float4 a = *(const float4*)(x + i), b = *(const float4*)(x + i + 4);
            ushort4 u0 = {f2bf(a.x), f2bf(a.y), f2bf(a.z), f2bf(a.w)};
            ushort4 u1 = {f2bf(b.x), f2bf(b.y), f2bf(b.z), f2bf(b.w)};
            *(ushort4*)(xb + i) = u0;
            *(ushort4*)(xb + i + 4) = u1;
        }
        return;
    }
    const float* w = (z == 0) ? wq : (z == 1) ? wk : (z == 2) ? wv : wo;
    unsigned short* dst = (z == 3) ? wo_t : wqkv_t + (size_t)z * K * K;
    const int k0 = blockIdx.x * 64, n0 = blockIdx.y * 64;
    #pragma unroll
    for (int it = 0; it < 16; ++it) {
        int idx = t + it * 256;
        tile[idx >> 6][idx & 63] = w[(size_t)(k0 + (idx >> 6)) * K + n0 + (idx & 63)];
    }
    __syncthreads();
    #pragma unroll
    for (int it = 0; it < 16; ++it) {
        int idx = t + it * 256;
        int r = idx >> 6, c = idx & 63;
        dst[(size_t)(n0 + r) * K + k0 + c] = f2bf(tile[c][r]);
    }
}

// ---------------------------------------------------------------------------
// Fused QKV MFMA GEMM (BK=32 single-buffer) + 2-bit LDS slot swizzle:
// rows of [128][32] are 64B (16 banks) -> unswizzled fragment reads are
// 8-way conflicted (bank = 16*lr mod 32). slot ^= row&3 spreads to 4-way.
// Applied both-sides: inverse-swizzled gload source col + swizzled ds_read.
// Q written PRE-SCALED by 0.125*log2(e) (exp2-domain attention).
// ---------------------------------------------------------------------------
__global__ __launch_bounds__(256) void qkv_mfma_kernel(
    const unsigned short* __restrict__ xa, const unsigned short* __restrict__ bt,
    unsigned short* __restrict__ q, unsigned short* __restrict__ k,
    unsigned short* __restrict__ vt)
{
    __shared__ unsigned short A_lds[128][32];
    __shared__ unsigned short B_lds[128][32];
    const int t = threadIdx.x, w = t >> 6, l = t & 63;
    const int lr = l & 15, lg = l >> 4;
    const int wm = w >> 1, wn = w & 1;
    const int m0 = blockIdx.x * 128, n0 = blockIdx.y * 128;
    const int srow = l >> 2;
    const int skofs = (((l & 3) ^ ((l >> 2) & 3))) * 8;   // inverse-swz source
    const int rslot = (lg ^ (lr & 3)) * 8;                // swizzled read col

    f32x4 acc[4][4];
    #pragma unroll
    for (int i = 0; i < 4; ++i)
        #pragma unroll
        for (int j = 0; j < 4; ++j) acc[i][j] = (f32x4){0.f, 0.f, 0.f, 0.f};

    for (int k0 = 0; k0 < K; k0 += 32) {
        #pragma unroll
        for (int p = 0; p < 2; ++p) {
            const int c = w * 2 + p;
            gload_lds16(xa + (size_t)(m0 + c * 16 + srow) * K + k0 + skofs, &A_lds[c * 16][0]);
            gload_lds16(bt + (size_t)(n0 + c * 16 + srow) * K + k0 + skofs, &B_lds[c * 16][0]);
        }
        __syncthreads();
        short8 af[4], bf[4];
        #pragma unroll
        for (int i = 0; i < 4; ++i) af[i] = *(const short8*)&A_lds[wm * 64 + i * 16 + lr][rslot];
        #pragma unroll
        for (int j = 0; j < 4; ++j) bf[j] = *(const short8*)&B_lds[wn * 64 + j * 16 + lr][rslot];
        #pragma unroll
        for (int i = 0; i < 4; ++i)
            #pragma unroll
            for (int j = 0; j < 4; ++j)
                acc[i][j] = __builtin_amdgcn_mfma_f32_16x16x32_bf16(af[i], bf[j], acc[i][j], 0, 0, 0);
        __syncthreads();
    }

    const int z = (n0 >> 10);
    const float scale = (z == 0) ? 0.125f * 1.44269504f : 1.0f;
    #pragma unroll
    for (int i = 0; i < 4; ++i) {
        const int mbase = m0 + wm * 64 + i * 16 + lg * 4;
        #pragma unroll
        for (int j = 0; j < 4; ++j) {
            const int n = n0 + wn * 64 + j * 16 + lr;
            const int nn = n & 1023, hh = nn >> 6, hd = nn & 63;
            #pragma unroll
            for (int r = 0; r < 4; ++r) {
                const int mm = mbase + r, bb = mm >> 11, ss = mm & (S - 1);
                const unsigned short val = f2bf(acc[i][j][r] * scale);
                if (z == 0)      q[((size_t)(bb * H + hh) * S + ss) * Hd + hd] = val;
                else if (z == 1) k[((size_t)(bb * H + hh) * S + ss) * Hd + hd] = val;
                else             vt[((size_t)(bb * H + hh) * Hd + hd) * S + ss] = val;
            }
        }
    }
}

// ---------------------------------------------------------------------------
// Output projection MFMA GEMM (BK=32 single-buffer) + same slot swizzle.
// ---------------------------------------------------------------------------
__global__ __launch_bounds__(256) void out_mfma_kernel(
    const unsigned short* __restrict__ a, const unsigned short* __restrict__ bt,
    const float* __restrict__ bias, float* __restrict__ out)
{
    __shared__ unsigned short A_lds[128][32];
    __shared__ unsigned short B_lds[128][32];
    const int t = threadIdx.x, w = t >> 6, l = t & 63;
    const int lr = l & 15, lg = l >> 4;
    const int wm = w >> 1, wn = w & 1;
    const int m0 = blockIdx.x * 128, n0 = blockIdx.y * 128;
    const int srow = l >> 2;
    const int skofs = (((l & 3) ^ ((l >> 2) & 3))) * 8;
    const int rslot = (lg ^ (lr & 3)) * 8;

    f32x4 acc[4][4];
    #pragma unroll
    for (int i = 0; i < 4; ++i)
        #pragma unroll
        for (int j = 0; j < 4; ++j) acc[i][j] = (f32x4){0.f, 0.f, 0.f, 0.f};

    for (int k0 = 0; k0 < K; k0 += 32) {
        #pragma unroll
        for (int p = 0; p < 2; ++p) {
            const int c = w * 2 + p;
            gload_lds16(a  + (size_t)(m0 + c * 16 + srow) * K + k0 + skofs, &A_lds[c * 16][0]);
            gload_lds16(bt + (size_t)(n0 + c * 16 + srow) * K + k0 + skofs, &B_lds[c * 16][0]);
        }
        __syncthreads();
        short8 af[4], bf[4];
        #pragma unroll
        for (int i = 0; i < 4; ++i) af[i] = *(const short8*)&A_lds[wm * 64 + i * 16 + lr][rslot];
        #pragma unroll
        for (int j = 0; j < 4; ++j) bf[j] = *(const short8*)&B_lds[wn * 64 + j * 16 + lr][rslot];
        #pragma unroll
        for (int i = 0; i < 4; ++i)
            #pragma unroll
            for (int j = 0; j < 4; ++j)
                acc[i][j] = __builtin_amdgcn_mfma_f32_16x16x32_bf16(af[i], bf[j], acc[i][j], 0, 0, 0);
        __syncthreads();
    }

    #pragma unroll
    for (int i = 0; i < 4; ++i) {
        const int mbase = m0 + wm * 64 + i * 16 + lg * 4;
        #pragma unroll
        for (int j = 0; j < 4; ++j) {
            const int n = n0 + wn * 64 + j * 16 + lr;
            const float bv = bias[n];
            #pragma unroll
            for (int r = 0; r < 4; ++r)
                out[(size_t)(mbase + r) * D + n] = acc[i][j][r] + bv;
        }
    }
}

// ---------------------------------------------------------------------------
// MFMA causal flash attention — UNCHANGED from R17 (passing, 44 µs):
// dbuf K/V one-barrier, peeled diag, fixed-reference exp2(s-16) softmax,
// XCD-locality grid, swizzled LDS, swapped QK^T + swapped PV.
// ---------------------------------------------------------------------------
__global__ __launch_bounds__(256) void attn_mfma_kernel(
    const unsigned short* __restrict__ q, const unsigned short* __restrict__ k,
    const unsigned short* __restrict__ vt, unsigned short* __restrict__ ctx)
{
    __shared__ unsigned short Kb[2][64 * 64];
    __shared__ unsigned short Vb[2][64 * 64];
    __shared__ unsigned short P_lds[4][16 * 64];
    const int t = threadIdx.x, w = t >> 6, l = t & 63;
    const int lr = l & 15, lg = l >> 4;

    const int bid = blockIdx.x;          // 0..1023
    const int xcd = bid & 7;
    const int j   = bid >> 3;            // 0..127
    const int m   = j >> 5;              // 0..3: bh-group within XCD
    const int c0  = j & 31;
    const int bh  = xcd * 4 + m;         // 0..31
    const int bb  = bh >> 4, hh = bh & 15;
    const int cc  = (c0 + ((m >> 1) ? 8 : 0)) & 31;
    const int qt  = (m & 1) ? (31 - cc) : cc;

    const int q0 = qt * 64 + w * 16;
    const int diag = qt;
    const size_t base  = (size_t)(bb * H + hh) * S * Hd;
    const size_t vbase = (size_t)(bb * H + hh) * Hd * S;
    const int pswz = (lr & 7) << 3;

    const int srow0 = w * 16 + (l >> 3);
    const int scol  = (l & 7) * 8;

    short8 qf[2];
    #pragma unroll
    for (int ci = 0; ci < 2; ++ci)
        qf[ci] = *(const short8*)(q + base + (size_t)(q0 + lr) * Hd + ci * 32 + lg * 8);

    f32x4 accO[4];
    #pragma unroll
    for (int hb = 0; hb < 4; ++hb) accO[hb] = (f32x4){0.f, 0.f, 0.f, 0.f};
    float l_part = 0.f;

    {
        short8 k0r[2], v0r[2];
        #pragma unroll
        for (int it = 0; it < 2; ++it) {
            const int row = srow0 + it * 8;
            k0r[it] = *(const short8*)(k + base + (size_t)row * Hd + scol);
            v0r[it] = *(const short8*)(vt + vbase + (size_t)row * S + scol);
        }
        #pragma unroll
        for (int it = 0; it < 2; ++it) {
            const int row = srow0 + it * 8;
            const int wc = (scol ^ ((row & 7) * 8));
            *(short8*)&Kb[0][row * 64 + wc] = k0r[it];
            *(short8*)&Vb[0][row * 64 + wc] = v0r[it];
        }
    }
    __syncthreads();

    int cur = 0;
    for (int kt = 0; kt < diag; ++kt) {
        short8 nK[2], nV[2];
        {
            const unsigned short* kg = k + base + (size_t)(kt + 1) * 64 * Hd;
            const unsigned short* vg = vt + vbase + (size_t)(kt + 1) * 64;
            #pragma unroll
            for (int it = 0; it < 2; ++it) {
                const int row = srow0 + it * 8;
                nK[it] = *(const short8*)(kg + (size_t)row * Hd + scol);
                nV[it] = *(const short8*)(vg + (size_t)row * S + scol);
            }
        }

        const unsigned short* Kc = Kb[cur];
        const unsigned short* Vc = Vb[cur];

        f32x4 accS[4];
        __builtin_amdgcn_s_setprio(1);
        #pragma unroll
        for (int kc = 0; kc < 4; ++kc) {
            accS[kc] = (f32x4){0.f, 0.f, 0.f, 0.f};
            const int krow = kc * 16 + lr;
            #pragma unroll
            for (int ci = 0; ci < 2; ++ci) {
                short8 kf = *(const short8*)&Kc[krow * 64 +
                    ((ci * 32 + lg * 8) ^ ((krow & 7) * 8))];
                accS[kc] = __builtin_amdgcn_mfma_f32_16x16x32_bf16(kf, qf[ci], accS[kc], 0, 0, 0);
            }
        }
        __builtin_amdgcn_s_setprio(0);

        float ps[16];
        #pragma unroll
        for (int i = 0; i < 16; ++i)
            ps[i] = EXP2F(accS[i >> 2][i & 3] - 16.f);
        float s8[8];
        #pragma unroll
        for (int i = 0; i < 8; ++i) s8[i] = ps[i] + ps[i + 8];
        l_part += ((s8[0] + s8[4]) + (s8[1] + s8[5])) +
                  ((s8[2] + s8[6]) + (s8[3] + s8[7]));

        #pragma unroll
        for (int kc = 0; kc < 4; ++kc) {
            uint2 pk;
            *(__hip_bfloat162*)&pk.x =
                __float22bfloat162_rn(make_float2(ps[kc * 4 + 0], ps[kc * 4 + 1]));
            *(__hip_bfloat162*)&pk.y =
                __float22bfloat162_rn(make_float2(ps[kc * 4 + 2], ps[kc * 4 + 3]));
            *(uint2*)&P_lds[w][lr * 64 + ((kc * 16 + lg * 4) ^ pswz)] = pk;
        }
        short8 pa[2];
        #pragma unroll
        for (int ci = 0; ci < 2; ++ci)
            pa[ci] = *(const short8*)&P_lds[w][lr * 64 + ((ci * 32 + lg * 8) ^ pswz)];

        __builtin_amdgcn_s_setprio(1);
        #pragma unroll
        for (int hb = 0; hb < 4; ++hb) {
            const int vrow = hb * 16 + lr;
            #pragma unroll
            for (int ci = 0; ci < 2; ++ci) {
                short8 vf = *(const short8*)&Vc[vrow * 64 +
                    ((ci * 32 + lg * 8) ^ ((vrow & 7) * 8))];
                accO[hb] = __builtin_amdgcn_mfma_f32_16x16x32_bf16(vf, pa[ci], accO[hb], 0, 0, 0);
            }
        }
        __builtin_amdgcn_s_setprio(0);

        #pragma unroll
        for (int it = 0; it < 2; ++it) {
            const int row = srow0 + it * 8;
            const int wc = (scol ^ ((row & 7) * 8));
            *(short8*)&Kb[cur ^ 1][row * 64 + wc] = nK[it];
            *(short8*)&Vb[cur ^ 1][row * 64 + wc] = nV[it];
        }
        __syncthreads();
        cur ^= 1;
    }

    {
        const unsigned short* Kc = Kb[cur];
        const unsigned short* Vc = Vb[cur];
        f32x4 accS[4];
        __builtin_amdgcn_s_setprio(1);
        #pragma unroll
        for (int kc = 0; kc < 4; ++kc) {
            accS[kc] = (f32x4){0.f, 0.f, 0.f, 0.f};
            const int krow = kc * 16 + lr;
            #pragma unroll
            for (int ci = 0; ci < 2; ++ci) {
                short8 kf = *(const short8*)&Kc[krow * 64 +
                    ((ci * 32 + lg * 8) ^ ((krow & 7) * 8))];
                accS[kc] = __builtin_amdgcn_mfma_f32_16x16x32_bf16(kf, qf[ci], accS[kc], 0, 0, 0);
            }
        }
        __builtin_amdgcn_s_setprio(0);

        float ps[16];
        #pragma unroll
        for (int kc = 0; kc < 4; ++kc)
            #pragma unroll
            for (int r = 0; r < 4; ++r) {
                float s = accS[kc][r];
                if (kc * 16 + lg * 4 + r > w * 16 + lr) s = -INFINITY;
                ps[kc * 4 + r] = EXP2F(s - 16.f);
            }
        float s8[8];
        #pragma unroll
        for (int i = 0; i < 8; ++i) s8[i] = ps[i] + ps[i + 8];
        l_part += ((s8[0] + s8[4]) + (s8[1] + s8[5])) +
                  ((s8[2] + s8[6]) + (s8[3] + s8[7]));

        #pragma unroll
        for (int kc = 0; kc < 4; ++kc) {
            uint2 pk;
            *(__hip_bfloat162*)&pk.x =
                __float22bfloat162_rn(make_float2(ps[kc * 4 + 0], ps[kc * 4 + 1]));
            *(__hip_bfloat162*)&pk.y =
                __float22bfloat162_rn(make_float2(ps[kc * 4 + 2], ps[kc * 4 + 3]));
            *(uint2*)&P_lds[w][lr * 64 + ((kc * 16 + lg * 4) ^ pswz)] = pk;
        }
        short8 pa[2];
        #pragma unroll
        for (int ci = 0; ci < 2; ++ci)
            pa[ci] = *(const short8*)&P_lds[w][lr * 64 + ((ci * 32 + lg * 8) ^ pswz)];

        __builtin_amdgcn_s_setprio(1);
        #pragma unroll
        for (int hb = 0; hb < 4; ++hb) {
            const int vrow = hb * 16 + lr;
            #pragma unroll
            for (int ci = 0; ci < 2; ++ci) {
                short8 vf = *(const short8*)&Vc[vrow * 64 +
                    ((ci * 32 + lg * 8) ^ ((vrow & 7) * 8))];
                accO[hb] = __builtin_amdgcn_mfma_f32_16x16x32_bf16(vf, pa[ci], accO[hb], 0, 0, 0);
            }
        }
        __builtin_amdgcn_s_setprio(0);
    }

    float l_run = l_part;
    l_run += __shfl_xor(l_run, 16);
    l_run += __shfl_xor(l_run, 32);
    const float inv = 1.f / l_run;
    unsigned short* crow = ctx + (size_t)(bb * S + q0 + lr) * D + hh * Hd + lg * 4;
    #pragma unroll
    for (int hb = 0; hb < 4; ++hb) {
        ushort4 o;
        o.x = f2bf(accO[hb][0] * inv);
        o.y = f2bf(accO[hb][1] * inv);
        o.z = f2bf(accO[hb][2] * inv);
        o.w = f2bf(accO[hb][3] * inv);
        *(ushort4*)(crow + hb * 16) = o;
    }
}

extern "C" void kernel_launch(void* const* d_in, const int* in_sizes, int n_in,
                              void* d_out, int out_size, void* d_ws, size_t ws_size,
                              hipStream_t stream) {
    const float* x  = (const float*)d_in[0];
    const float* wq = (const float*)d_in[1];
    const float* wk = (const float*)d_in[2];
    const float* wv = (const float*)d_in[3];
    const float* wo = (const float*)d_in[4];
    const float* bo = (const float*)d_in[5];
    float* out = (float*)d_out;

    char* ws = (char*)d_ws;
    unsigned short* x_bf   = (unsigned short*)ws;
    unsigned short* q      = (unsigned short*)(ws + ((size_t)8  << 20));
    unsigned short* kk     = (unsigned short*)(ws + ((size_t)16 << 20));
    unsigned short* vt     = (unsigned short*)(ws + ((size_t)24 << 20));
    unsigned short* ctx    = x_bf;
    unsigned short* wqkv_t = (unsigned short*)(ws + ((size_t)32 << 20));
    unsigned short* wo_t   = (unsigned short*)(ws + ((size_t)38 << 20));

    dim3 gprep(16, 16, 5);
    prep_kernel<<<gprep, 256, 0, stream>>>(x, wq, wk, wv, wo, x_bf, wqkv_t, wo_t);

    dim3 gqkv(M / 128, 3072 / 128);
    qkv_mfma_kernel<<<gqkv, 256, 0, stream>>>(x_bf, wqkv_t, q, kk, vt);

    attn_mfma_kernel<<<1024, 256, 0, stream>>>(q, kk, vt, ctx);

    dim3 gout(M / 128, D / 128);
    out_mfma_kernel<<<gout, 256, 0, stream>>>(ctx, wo_t, bo, out);
}

// Round 19
// 110.756 us; speedup vs baseline: 1.0322x; 1.0016x over previous
//
#include <hip/hip_runtime.h>
#include <hip/hip_bf16.h>

constexpr int B = 2, S = 2048, D = 1024, H = 16, Hd = 64;
constexpr int M = B * S;   // 4096 rows
constexpr int K = 1024;

typedef __attribute__((ext_vector_type(8))) short short8;
typedef __attribute__((ext_vector_type(4))) float f32x4;

#if __has_builtin(__builtin_amdgcn_exp2f)
#define EXP2F __builtin_amdgcn_exp2f
#else
#define EXP2F exp2f
#endif

__device__ __forceinline__ float bf2f(unsigned short u) {
    return __uint_as_float(((unsigned)u) << 16);
}
__device__ __forceinline__ unsigned short f2bf(float f) {   // RNE
    unsigned u = __float_as_uint(f);
    u += 0x7FFF + ((u >> 16) & 1);
    return (unsigned short)(u >> 16);
}
__device__ __forceinline__ void gload_lds16(const unsigned short* g, unsigned short* l) {
    __builtin_amdgcn_global_load_lds(
        (const __attribute__((address_space(1))) void*)g,
        (__attribute__((address_space(3))) void*)l, 16, 0, 0);
}

// ---------------------------------------------------------------------------
// Prep: z=0..3 -> weight transpose+convert (w [K,N] fp32 -> wt [N,K] bf16);
//       z=4    -> x fp32 -> bf16. One launch instead of two.
// ---------------------------------------------------------------------------
__global__ __launch_bounds__(256) void prep_kernel(
    const float* __restrict__ x,
    const float* __restrict__ wq, const float* __restrict__ wk,
    const float* __restrict__ wv, const float* __restrict__ wo,
    unsigned short* __restrict__ xb,
    unsigned short* __restrict__ wqkv_t, unsigned short* __restrict__ wo_t)
{
    __shared__ float tile[64][65];
    const int z = blockIdx.z;
    const int t = threadIdx.x;
    if (z == 4) {   // x conversion: 256 blocks x 256 thr x 8 iters x 8 elems
        const int bid = blockIdx.y * 16 + blockIdx.x;
        const size_t base_i = ((size_t)bid * 256 + t) * 8;
        #pragma unroll
        for (int it = 0; it < 8; ++it) {
            const size_t i = base_i + (size_t)it * 524288;
            float4 a = *(const float4*)(x + i), b = *(const float4*)(x + i + 4);
            ushort4 u0 = {f2bf(a.x), f2bf(a.y), f2bf(a.z), f2bf(a.w)};
            ushort4 u1 = {f2bf(b.x), f2bf(b.y), f2bf(b.z), f2bf(b.w)};
            *(ushort4*)(xb + i) = u0;
            *(ushort4*)(xb + i + 4) = u1;
        }
        return;
    }
    const float* w = (z == 0) ? wq : (z == 1) ? wk : (z == 2) ? wv : wo;
    unsigned short* dst = (z == 3) ? wo_t : wqkv_t + (size_t)z * K * K;
    const int k0 = blockIdx.x * 64, n0 = blockIdx.y * 64;
    #pragma unroll
    for (int it = 0; it < 16; ++it) {
        int idx = t + it * 256;
        tile[idx >> 6][idx & 63] = w[(size_t)(k0 + (idx >> 6)) * K + n0 + (idx & 63)];
    }
    __syncthreads();
    #pragma unroll
    for (int it = 0; it < 16; ++it) {
        int idx = t + it * 256;
        int r = idx >> 6, c = idx & 63;
        dst[(size_t)(n0 + r) * K + k0 + c] = f2bf(tile[c][r]);
    }
}

// ---------------------------------------------------------------------------
// Fused QKV MFMA GEMM (BK=32 single-buffer) + 2-bit LDS slot swizzle:
// rows of [128][32] are 64B (16 banks) -> unswizzled fragment reads are
// 8-way conflicted (bank = 16*lr mod 32). slot ^= row&3 spreads to 4-way.
// Applied both-sides: inverse-swizzled gload source col + swizzled ds_read.
// Q written PRE-SCALED by 0.125*log2(e) (exp2-domain attention).
// ---------------------------------------------------------------------------
__global__ __launch_bounds__(256) void qkv_mfma_kernel(
    const unsigned short* __restrict__ xa, const unsigned short* __restrict__ bt,
    unsigned short* __restrict__ q, unsigned short* __restrict__ k,
    unsigned short* __restrict__ vt)
{
    __shared__ unsigned short A_lds[128][32];
    __shared__ unsigned short B_lds[128][32];
    const int t = threadIdx.x, w = t >> 6, l = t & 63;
    const int lr = l & 15, lg = l >> 4;
    const int wm = w >> 1, wn = w & 1;
    const int m0 = blockIdx.x * 128, n0 = blockIdx.y * 128;
    const int srow = l >> 2;
    const int skofs = (((l & 3) ^ ((l >> 2) & 3))) * 8;   // inverse-swz source
    const int rslot = (lg ^ (lr & 3)) * 8;                // swizzled read col

    f32x4 acc[4][4];
    #pragma unroll
    for (int i = 0; i < 4; ++i)
        #pragma unroll
        for (int j = 0; j < 4; ++j) acc[i][j] = (f32x4){0.f, 0.f, 0.f, 0.f};

    for (int k0 = 0; k0 < K; k0 += 32) {
        #pragma unroll
        for (int p = 0; p < 2; ++p) {
            const int c = w * 2 + p;
            gload_lds16(xa + (size_t)(m0 + c * 16 + srow) * K + k0 + skofs, &A_lds[c * 16][0]);
            gload_lds16(bt + (size_t)(n0 + c * 16 + srow) * K + k0 + skofs, &B_lds[c * 16][0]);
        }
        __syncthreads();
        short8 af[4], bf[4];
        #pragma unroll
        for (int i = 0; i < 4; ++i) af[i] = *(const short8*)&A_lds[wm * 64 + i * 16 + lr][rslot];
        #pragma unroll
        for (int j = 0; j < 4; ++j) bf[j] = *(const short8*)&B_lds[wn * 64 + j * 16 + lr][rslot];
        #pragma unroll
        for (int i = 0; i < 4; ++i)
            #pragma unroll
            for (int j = 0; j < 4; ++j)
                acc[i][j] = __builtin_amdgcn_mfma_f32_16x16x32_bf16(af[i], bf[j], acc[i][j], 0, 0, 0);
        __syncthreads();
    }

    const int z = (n0 >> 10);
    const float scale = (z == 0) ? 0.125f * 1.44269504f : 1.0f;
    #pragma unroll
    for (int i = 0; i < 4; ++i) {
        const int mbase = m0 + wm * 64 + i * 16 + lg * 4;
        #pragma unroll
        for (int j = 0; j < 4; ++j) {
            const int n = n0 + wn * 64 + j * 16 + lr;
            const int nn = n & 1023, hh = nn >> 6, hd = nn & 63;
            #pragma unroll
            for (int r = 0; r < 4; ++r) {
                const int mm = mbase + r, bb = mm >> 11, ss = mm & (S - 1);
                const unsigned short val = f2bf(acc[i][j][r] * scale);
                if (z == 0)      q[((size_t)(bb * H + hh) * S + ss) * Hd + hd] = val;
                else if (z == 1) k[((size_t)(bb * H + hh) * S + ss) * Hd + hd] = val;
                else             vt[((size_t)(bb * H + hh) * Hd + hd) * S + ss] = val;
            }
        }
    }
}

// ---------------------------------------------------------------------------
// Output projection MFMA GEMM (BK=32 single-buffer) + same slot swizzle.
// ---------------------------------------------------------------------------
__global__ __launch_bounds__(256) void out_mfma_kernel(
    const unsigned short* __restrict__ a, const unsigned short* __restrict__ bt,
    const float* __restrict__ bias, float* __restrict__ out)
{
    __shared__ unsigned short A_lds[128][32];
    __shared__ unsigned short B_lds[128][32];
    const int t = threadIdx.x, w = t >> 6, l = t & 63;
    const int lr = l & 15, lg = l >> 4;
    const int wm = w >> 1, wn = w & 1;
    const int m0 = blockIdx.x * 128, n0 = blockIdx.y * 128;
    const int srow = l >> 2;
    const int skofs = (((l & 3) ^ ((l >> 2) & 3))) * 8;
    const int rslot = (lg ^ (lr & 3)) * 8;

    f32x4 acc[4][4];
    #pragma unroll
    for (int i = 0; i < 4; ++i)
        #pragma unroll
        for (int j = 0; j < 4; ++j) acc[i][j] = (f32x4){0.f, 0.f, 0.f, 0.f};

    for (int k0 = 0; k0 < K; k0 += 32) {
        #pragma unroll
        for (int p = 0; p < 2; ++p) {
            const int c = w * 2 + p;
            gload_lds16(a  + (size_t)(m0 + c * 16 + srow) * K + k0 + skofs, &A_lds[c * 16][0]);
            gload_lds16(bt + (size_t)(n0 + c * 16 + srow) * K + k0 + skofs, &B_lds[c * 16][0]);
        }
        __syncthreads();
        short8 af[4], bf[4];
        #pragma unroll
        for (int i = 0; i < 4; ++i) af[i] = *(const short8*)&A_lds[wm * 64 + i * 16 + lr][rslot];
        #pragma unroll
        for (int j = 0; j < 4; ++j) bf[j] = *(const short8*)&B_lds[wn * 64 + j * 16 + lr][rslot];
        #pragma unroll
        for (int i = 0; i < 4; ++i)
            #pragma unroll
            for (int j = 0; j < 4; ++j)
                acc[i][j] = __builtin_amdgcn_mfma_f32_16x16x32_bf16(af[i], bf[j], acc[i][j], 0, 0, 0);
        __syncthreads();
    }

    #pragma unroll
    for (int i = 0; i < 4; ++i) {
        const int mbase = m0 + wm * 64 + i * 16 + lg * 4;
        #pragma unroll
        for (int j = 0; j < 4; ++j) {
            const int n = n0 + wn * 64 + j * 16 + lr;
            const float bv = bias[n];
            #pragma unroll
            for (int r = 0; r < 4; ++r)
                out[(size_t)(mbase + r) * D + n] = acc[i][j][r] + bv;
        }
    }
}

// ---------------------------------------------------------------------------
// MFMA causal flash attention — UNCHANGED from R17 (passing, 44 µs):
// dbuf K/V one-barrier, peeled diag, fixed-reference exp2(s-16) softmax,
// XCD-locality grid, swizzled LDS, swapped QK^T + swapped PV.
// ---------------------------------------------------------------------------
__global__ __launch_bounds__(256) void attn_mfma_kernel(
    const unsigned short* __restrict__ q, const unsigned short* __restrict__ k,
    const unsigned short* __restrict__ vt, unsigned short* __restrict__ ctx)
{
    __shared__ unsigned short Kb[2][64 * 64];
    __shared__ unsigned short Vb[2][64 * 64];
    __shared__ unsigned short P_lds[4][16 * 64];
    const int t = threadIdx.x, w = t >> 6, l = t & 63;
    const int lr = l & 15, lg = l >> 4;

    const int bid = blockIdx.x;          // 0..1023
    const int xcd = bid & 7;
    const int j   = bid >> 3;            // 0..127
    const int m   = j >> 5;              // 0..3: bh-group within XCD
    const int c0  = j & 31;
    const int bh  = xcd * 4 + m;         // 0..31
    const int bb  = bh >> 4, hh = bh & 15;
    const int cc  = (c0 + ((m >> 1) ? 8 : 0)) & 31;
    const int qt  = (m & 1) ? (31 - cc) : cc;

    const int q0 = qt * 64 + w * 16;
    const int diag = qt;
    const size_t base  = (size_t)(bb * H + hh) * S * Hd;
    const size_t vbase = (size_t)(bb * H + hh) * Hd * S;
    const int pswz = (lr & 7) << 3;

    const int srow0 = w * 16 + (l >> 3);
    const int scol  = (l & 7) * 8;

    short8 qf[2];
    #pragma unroll
    for (int ci = 0; ci < 2; ++ci)
        qf[ci] = *(const short8*)(q + base + (size_t)(q0 + lr) * Hd + ci * 32 + lg * 8);

    f32x4 accO[4];
    #pragma unroll
    for (int hb = 0; hb < 4; ++hb) accO[hb] = (f32x4){0.f, 0.f, 0.f, 0.f};
    float l_part = 0.f;

    {
        short8 k0r[2], v0r[2];
        #pragma unroll
        for (int it = 0; it < 2; ++it) {
            const int row = srow0 + it * 8;
            k0r[it] = *(const short8*)(k + base + (size_t)row * Hd + scol);
            v0r[it] = *(const short8*)(vt + vbase + (size_t)row * S + scol);
        }
        #pragma unroll
        for (int it = 0; it < 2; ++it) {
            const int row = srow0 + it * 8;
            const int wc = (scol ^ ((row & 7) * 8));
            *(short8*)&Kb[0][row * 64 + wc] = k0r[it];
            *(short8*)&Vb[0][row * 64 + wc] = v0r[it];
        }
    }
    __syncthreads();

    int cur = 0;
    for (int kt = 0; kt < diag; ++kt) {
        short8 nK[2], nV[2];
        {
            const unsigned short* kg = k + base + (size_t)(kt + 1) * 64 * Hd;
            const unsigned short* vg = vt + vbase + (size_t)(kt + 1) * 64;
            #pragma unroll
            for (int it = 0; it < 2; ++it) {
                const int row = srow0 + it * 8;
                nK[it] = *(const short8*)(kg + (size_t)row * Hd + scol);
                nV[it] = *(const short8*)(vg + (size_t)row * S + scol);
            }
        }

        const unsigned short* Kc = Kb[cur];
        const unsigned short* Vc = Vb[cur];

        f32x4 accS[4];
        __builtin_amdgcn_s_setprio(1);
        #pragma unroll
        for (int kc = 0; kc < 4; ++kc) {
            accS[kc] = (f32x4){0.f, 0.f, 0.f, 0.f};
            const int krow = kc * 16 + lr;
            #pragma unroll
            for (int ci = 0; ci < 2; ++ci) {
                short8 kf = *(const short8*)&Kc[krow * 64 +
                    ((ci * 32 + lg * 8) ^ ((krow & 7) * 8))];
                accS[kc] = __builtin_amdgcn_mfma_f32_16x16x32_bf16(kf, qf[ci], accS[kc], 0, 0, 0);
            }
        }
        __builtin_amdgcn_s_setprio(0);

        float ps[16];
        #pragma unroll
        for (int i = 0; i < 16; ++i)
            ps[i] = EXP2F(accS[i >> 2][i & 3] - 16.f);
        float s8[8];
        #pragma unroll
        for (int i = 0; i < 8; ++i) s8[i] = ps[i] + ps[i + 8];
        l_part += ((s8[0] + s8[4]) + (s8[1] + s8[5])) +
                  ((s8[2] + s8[6]) + (s8[3] + s8[7]));

        #pragma unroll
        for (int kc = 0; kc < 4; ++kc) {
            uint2 pk;
            *(__hip_bfloat162*)&pk.x =
                __float22bfloat162_rn(make_float2(ps[kc * 4 + 0], ps[kc * 4 + 1]));
            *(__hip_bfloat162*)&pk.y =
                __float22bfloat162_rn(make_float2(ps[kc * 4 + 2], ps[kc * 4 + 3]));
            *(uint2*)&P_lds[w][lr * 64 + ((kc * 16 + lg * 4) ^ pswz)] = pk;
        }
        short8 pa[2];
        #pragma unroll
        for (int ci = 0; ci < 2; ++ci)
            pa[ci] = *(const short8*)&P_lds[w][lr * 64 + ((ci * 32 + lg * 8) ^ pswz)];

        __builtin_amdgcn_s_setprio(1);
        #pragma unroll
        for (int hb = 0; hb < 4; ++hb) {
            const int vrow = hb * 16 + lr;
            #pragma unroll
            for (int ci = 0; ci < 2; ++ci) {
                short8 vf = *(const short8*)&Vc[vrow * 64 +
                    ((ci * 32 + lg * 8) ^ ((vrow & 7) * 8))];
                accO[hb] = __builtin_amdgcn_mfma_f32_16x16x32_bf16(vf, pa[ci], accO[hb], 0, 0, 0);
            }
        }
        __builtin_amdgcn_s_setprio(0);

        #pragma unroll
        for (int it = 0; it < 2; ++it) {
            const int row = srow0 + it * 8;
            const int wc = (scol ^ ((row & 7) * 8));
            *(short8*)&Kb[cur ^ 1][row * 64 + wc] = nK[it];
            *(short8*)&Vb[cur ^ 1][row * 64 + wc] = nV[it];
        }
        __syncthreads();
        cur ^= 1;
    }

    {
        const unsigned short* Kc = Kb[cur];
        const unsigned short* Vc = Vb[cur];
        f32x4 accS[4];
        __builtin_amdgcn_s_setprio(1);
        #pragma unroll
        for (int kc = 0; kc < 4; ++kc) {
            accS[kc] = (f32x4){0.f, 0.f, 0.f, 0.f};
            const int krow = kc * 16 + lr;
            #pragma unroll
            for (int ci = 0; ci < 2; ++ci) {
                short8 kf = *(const short8*)&Kc[krow * 64 +
                    ((ci * 32 + lg * 8) ^ ((krow & 7) * 8))];
                accS[kc] = __builtin_amdgcn_mfma_f32_16x16x32_bf16(kf, qf[ci], accS[kc], 0, 0, 0);
            }
        }
        __builtin_amdgcn_s_setprio(0);

        float ps[16];
        #pragma unroll
        for (int kc = 0; kc < 4; ++kc)
            #pragma unroll
            for (int r = 0; r < 4; ++r) {
                float s = accS[kc][r];
                if (kc * 16 + lg * 4 + r > w * 16 + lr) s = -INFINITY;
                ps[kc * 4 + r] = EXP2F(s - 16.f);
            }
        float s8[8];
        #pragma unroll
        for (int i = 0; i < 8; ++i) s8[i] = ps[i] + ps[i + 8];
        l_part += ((s8[0] + s8[4]) + (s8[1] + s8[5])) +
                  ((s8[2] + s8[6]) + (s8[3] + s8[7]));

        #pragma unroll
        for (int kc = 0; kc < 4; ++kc) {
            uint2 pk;
            *(__hip_bfloat162*)&pk.x =
                __float22bfloat162_rn(make_float2(ps[kc * 4 + 0], ps[kc * 4 + 1]));
            *(__hip_bfloat162*)&pk.y =
                __float22bfloat162_rn(make_float2(ps[kc * 4 + 2], ps[kc * 4 + 3]));
            *(uint2*)&P_lds[w][lr * 64 + ((kc * 16 + lg * 4) ^ pswz)] = pk;
        }
        short8 pa[2];
        #pragma unroll
        for (int ci = 0; ci < 2; ++ci)
            pa[ci] = *(const short8*)&P_lds[w][lr * 64 + ((ci * 32 + lg * 8) ^ pswz)];

        __builtin_amdgcn_s_setprio(1);
        #pragma unroll
        for (int hb = 0; hb < 4; ++hb) {
            const int vrow = hb * 16 + lr;
            #pragma unroll
            for (int ci = 0; ci < 2; ++ci) {
                short8 vf = *(const short8*)&Vc[vrow * 64 +
                    ((ci * 32 + lg * 8) ^ ((vrow & 7) * 8))];
                accO[hb] = __builtin_amdgcn_mfma_f32_16x16x32_bf16(vf, pa[ci], accO[hb], 0, 0, 0);
            }
        }
        __builtin_amdgcn_s_setprio(0);
    }

    float l_run = l_part;
    l_run += __shfl_xor(l_run, 16);
    l_run += __shfl_xor(l_run, 32);
    const float inv = 1.f / l_run;
    unsigned short* crow = ctx + (size_t)(bb * S + q0 + lr) * D + hh * Hd + lg * 4;
    #pragma unroll
    for (int hb = 0; hb < 4; ++hb) {
        ushort4 o;
        o.x = f2bf(accO[hb][0] * inv);
        o.y = f2bf(accO[hb][1] * inv);
        o.z = f2bf(accO[hb][2] * inv);
        o.w = f2bf(accO[hb][3] * inv);
        *(ushort4*)(crow + hb * 16) = o;
    }
}

extern "C" void kernel_launch(void* const* d_in, const int* in_sizes, int n_in,
                              void* d_out, int out_size, void* d_ws, size_t ws_size,
                              hipStream_t stream) {
    const float* x  = (const float*)d_in[0];
    const float* wq = (const float*)d_in[1];
    const float* wk = (const float*)d_in[2];
    const float* wv = (const float*)d_in[3];
    const float* wo = (const float*)d_in[4];
    const float* bo = (const float*)d_in[5];
    float* out = (float*)d_out;

    char* ws = (char*)d_ws;
    unsigned short* x_bf   = (unsigned short*)ws;
    unsigned short* q      = (unsigned short*)(ws + ((size_t)8  << 20));
    unsigned short* kk     = (unsigned short*)(ws + ((size_t)16 << 20));
    unsigned short* vt     = (unsigned short*)(ws + ((size_t)24 << 20));
    unsigned short* ctx    = x_bf;
    unsigned short* wqkv_t = (unsigned short*)(ws + ((size_t)32 << 20));
    unsigned short* wo_t   = (unsigned short*)(ws + ((size_t)38 << 20));

    dim3 gprep(16, 16, 5);
    prep_kernel<<<gprep, 256, 0, stream>>>(x, wq, wk, wv, wo, x_bf, wqkv_t, wo_t);

    dim3 gqkv(M / 128, 3072 / 128);
    qkv_mfma_kernel<<<gqkv, 256, 0, stream>>>(x_bf, wqkv_t, q, kk, vt);

    attn_mfma_kernel<<<1024, 256, 0, stream>>>(q, kk, vt, ctx);

    dim3 gout(M / 128, D / 128);
    out_mfma_kernel<<<gout, 256, 0, stream>>>(ctx, wo_t, bo, out);
}